// Round 1
// baseline (522.172 us; speedup 1.0000x reference)
//
#include <hip/hip_runtime.h>
#include <hip/hip_bf16.h>

#define N 8192
#define IN_F 512
#define OUT_F 128
#define ALPHA 0.2f
#define SPLITJ 4
#define JCHUNK (N / SPLITJ)   // 2048

typedef __attribute__((ext_vector_type(4))) float f32x4;
typedef __attribute__((ext_vector_type(8))) short bf16x8;   // 8 bf16 in 4 VGPRs

__device__ __forceinline__ short f2bf(float f) {
    union { float f; unsigned u; } c; c.f = f;
    unsigned r = c.u + 0x7FFFu + ((c.u >> 16) & 1u);   // round-to-nearest-even
    return (short)(r >> 16);
}
__device__ __forceinline__ float bf2f(short b) {
    union { float f; unsigned u; } c; c.u = ((unsigned)(unsigned short)b) << 16;
    return c.f;
}

// ---------------------------------------------------------------- P0: W -> WT (bf16, transposed [OUT_F][IN_F])
__global__ __launch_bounds__(256) void conv_W(const float* __restrict__ W, short* __restrict__ WT) {
    int idx = blockIdx.x * 256 + threadIdx.x;       // 65536 total
    int n = idx & (OUT_F - 1);
    int k = idx >> 7;
    WT[(size_t)n * IN_F + k] = f2bf(W[idx]);
}

// ---------------------------------------------------------------- P1: Wh = h @ W  -> WhT (bf16, [OUT_F][N])
// 4 waves/block, each wave: 16 rows x 128 cols, MFMA 16x16x32 bf16
__global__ __launch_bounds__(256) void gemm_hW(const float* __restrict__ h,
                                               const short* __restrict__ WT,
                                               short* __restrict__ WhT) {
    const int tid = threadIdx.x;
    const int wave = tid >> 6, lane = tid & 63;
    const int row16 = lane & 15, kgrp = lane >> 4;      // A: m=row16, k=kgrp*8+e
    const int i0 = blockIdx.x * 64 + wave * 16;
    const int m = i0 + row16;

    f32x4 acc[8] = {};

    for (int kk = 0; kk < IN_F; kk += 32) {
        const float4* hp = (const float4*)(h + (size_t)m * IN_F + kk + kgrp * 8);
        float4 h0 = hp[0], h1 = hp[1];
        bf16x8 af;
        af[0] = f2bf(h0.x); af[1] = f2bf(h0.y); af[2] = f2bf(h0.z); af[3] = f2bf(h0.w);
        af[4] = f2bf(h1.x); af[5] = f2bf(h1.y); af[6] = f2bf(h1.z); af[7] = f2bf(h1.w);
#pragma unroll
        for (int nt = 0; nt < 8; nt++) {
            bf16x8 bf_ = *(const bf16x8*)(WT + (size_t)(nt * 16 + row16) * IN_F + kk + kgrp * 8);
            acc[nt] = __builtin_amdgcn_mfma_f32_16x16x32_bf16(af, bf_, acc[nt], 0, 0, 0);
        }
    }
    // C layout: col = lane&15, row = kgrp*4 + r  -> Wh[i0+kgrp*4+r][nt*16+row16]
#pragma unroll
    for (int nt = 0; nt < 8; nt++) {
        short4 sv;
        sv.x = f2bf(acc[nt][0]); sv.y = f2bf(acc[nt][1]);
        sv.z = f2bf(acc[nt][2]); sv.w = f2bf(acc[nt][3]);
        *(short4*)(WhT + (size_t)(nt * 16 + row16) * N + i0 + kgrp * 4) = sv;
    }
}

// ---------------------------------------------------------------- P2: s = Wh@a1, t = Wh@a2
__global__ __launch_bounds__(256) void compute_st(const short* __restrict__ WhT,
                                                  const float* __restrict__ a,
                                                  float* __restrict__ s, float* __restrict__ t) {
    int m = blockIdx.x * 256 + threadIdx.x;
    float acc1 = 0.f, acc2 = 0.f;
    for (int n = 0; n < OUT_F; n++) {
        float v = bf2f(WhT[(size_t)n * N + m]);
        acc1 += v * a[n];
        acc2 += v * a[n + OUT_F];
    }
    s[m] = acc1; t[m] = acc2;
}

// ---------------------------------------------------------------- P3: fused masked softmax-weighted-sum
// grid (128, SPLITJ); 4 waves/block; wave = 16 rows; MFMA 16x16x32 bf16 over j
__global__ __launch_bounds__(256, 2) void attn(const int* __restrict__ adj,
                                               const short* __restrict__ WhT,
                                               const float* __restrict__ s,
                                               const float* __restrict__ t,
                                               float* __restrict__ num,
                                               float* __restrict__ lpart) {
    const int tid = threadIdx.x;
    const int wave = tid >> 6, lane = tid & 63;
    const int row16 = lane & 15, kgrp = lane >> 4;
    const int i0 = blockIdx.x * 64 + wave * 16;
    const int m = i0 + row16;
    const int sp = blockIdx.y;
    const int j0 = sp * JCHUNK;

    __shared__ float t_lds[JCHUNK];     // 8 KB
    for (int idx = tid; idx < JCHUNK; idx += 256) t_lds[idx] = t[j0 + idx];
    __syncthreads();

    const float s_m = s[m];
    f32x4 acc[8] = {};
    float lsum = 0.f;

    const int* aptr = adj + (size_t)m * N + j0 + kgrp * 8;
    int4 na0 = ((const int4*)aptr)[0];      // prefetch first step
    int4 na1 = ((const int4*)aptr)[1];

    for (int kk = 0; kk < JCHUNK; kk += 32) {
        int4 a0v = na0, a1v = na1;
        if (kk + 32 < JCHUNK) {             // prefetch next step's adj
            const int4* pf = (const int4*)(aptr + kk + 32);
            na0 = pf[0]; na1 = pf[1];
        }
        // B fragments: WhT[n][j0+kk+kgrp*8 .. +7], 16B contiguous per lane
        bf16x8 bfr[8];
        const short* bb = WhT + j0 + kk + kgrp * 8;
#pragma unroll
        for (int nt = 0; nt < 8; nt++)
            bfr[nt] = *(const bf16x8*)(bb + (size_t)(nt * 16 + row16) * N);

        const float* tp = t_lds + kk + kgrp * 8;
        float4 tA = *(const float4*)(tp);
        float4 tB = *(const float4*)(tp + 4);
        float tvls[8] = { tA.x, tA.y, tA.z, tA.w, tB.x, tB.y, tB.z, tB.w };
        int   avls[8] = { a0v.x, a0v.y, a0v.z, a0v.w, a1v.x, a1v.y, a1v.z, a1v.w };

        bf16x8 af;
#pragma unroll
        for (int e = 0; e < 8; e++) {
            float x = s_m + tvls[e];
            x = x > 0.f ? x : ALPHA * x;              // leaky relu
            float pv = avls[e] > 0 ? __expf(x) : 0.f; // masked exp (no max-sub needed)
            lsum += pv;
            af[e] = f2bf(pv);
        }
#pragma unroll
        for (int nt = 0; nt < 8; nt++)
            acc[nt] = __builtin_amdgcn_mfma_f32_16x16x32_bf16(af, bfr[nt], acc[nt], 0, 0, 0);
    }

    // row-sum of p across the 4 k-groups holding row m
    lsum += __shfl_xor(lsum, 16);
    lsum += __shfl_xor(lsum, 32);
    if (kgrp == 0) lpart[(size_t)sp * N + m] = lsum;

    // partial numerator [64 x 128] for this block
    float* np_ = num + ((size_t)sp * N + i0) * OUT_F;
#pragma unroll
    for (int nt = 0; nt < 8; nt++) {
#pragma unroll
        for (int r = 0; r < 4; r++)
            np_[(size_t)(kgrp * 4 + r) * OUT_F + nt * 16 + row16] = acc[nt][r];
    }
}

// ---------------------------------------------------------------- P4: reduce splits, divide, add rnd, elu
__global__ __launch_bounds__(256) void finalize(const float* __restrict__ num,
                                                const float* __restrict__ lpart,
                                                const float* __restrict__ rnd,
                                                float* __restrict__ out) {
    int idx = blockIdx.x * 256 + threadIdx.x;   // N*OUT_F
    int i = idx >> 7;
    float numer = 0.f, l = 0.f;
#pragma unroll
    for (int sp = 0; sp < SPLITJ; sp++) {
        numer += num[(size_t)sp * N * OUT_F + idx];
        l += lpart[(size_t)sp * N + i];
    }
    float hp = numer / fmaxf(l, 1e-30f);
    float x = (hp + rnd[idx]) * 1e-5f;
    out[idx] = x > 0.f ? x : __expf(x) - 1.f;
}

extern "C" void kernel_launch(void* const* d_in, const int* in_sizes, int n_in,
                              void* d_out, int out_size, void* d_ws, size_t ws_size,
                              hipStream_t stream) {
    const float* h   = (const float*)d_in[0];
    const int*   adj = (const int*)d_in[1];
    const float* W   = (const float*)d_in[2];
    const float* a   = (const float*)d_in[3];
    const float* rnd = (const float*)d_in[4];
    float* out = (float*)d_out;

    char* w = (char*)d_ws;
    short* WT    = (short*)(w);                    // 128*512*2  = 131072
    short* WhT   = (short*)(w + 131072);           // 128*8192*2 = 2097152
    float* sv    = (float*)(w + 2228224);          // 32768
    float* tv    = (float*)(w + 2260992);          // 32768
    float* lpart = (float*)(w + 2293760);          // 4*8192*4   = 131072
    float* num   = (float*)(w + 2424832);          // 4*8192*128*4 = 16777216  (end ~19.2 MB)

    conv_W    <<<256, 256, 0, stream>>>(W, WT);
    gemm_hW   <<<128, 256, 0, stream>>>(h, WT, WhT);
    compute_st<<<32, 256, 0, stream>>>(WhT, a, sv, tv);
    attn      <<<dim3(128, SPLITJ), 256, 0, stream>>>(adj, WhT, sv, tv, num, lpart);
    finalize  <<<(N * OUT_F) / 256, 256, 0, stream>>>(num, lpart, rnd, out);
}

// Round 2
// 497.032 us; speedup vs baseline: 1.0506x; 1.0506x over previous
//
#include <hip/hip_runtime.h>
#include <hip/hip_bf16.h>

#define N 8192
#define IN_F 512
#define OUT_F 128
#define ALPHA 0.2f

typedef __attribute__((ext_vector_type(4))) float f32x4;
typedef __attribute__((ext_vector_type(8))) short bf16x8;   // 8 bf16 in 4 VGPRs

__device__ __forceinline__ short f2bf(float f) {
    union { float f; unsigned u; } c; c.f = f;
    unsigned r = c.u + 0x7FFFu + ((c.u >> 16) & 1u);   // round-to-nearest-even
    return (short)(r >> 16);
}

// ---------------------------------------------------------------- P0: W -> WT (bf16, transposed [OUT_F][IN_F])
__global__ __launch_bounds__(256) void conv_W(const float* __restrict__ W, short* __restrict__ WT) {
    int idx = blockIdx.x * 256 + threadIdx.x;       // 65536 total
    int n = idx & (OUT_F - 1);
    int k = idx >> 7;
    WT[(size_t)n * IN_F + k] = f2bf(W[idx]);
}

// ---------------------------------------------------------------- P1: Wh = h@W -> WhT bf16 [OUT_F][N]; fused s,t
__global__ __launch_bounds__(256) void gemm_hW(const float* __restrict__ h,
                                               const short* __restrict__ WT,
                                               const float* __restrict__ a,
                                               short* __restrict__ WhT,
                                               float* __restrict__ sOut,
                                               float* __restrict__ tOut) {
    const int tid = threadIdx.x;
    const int wave = tid >> 6, lane = tid & 63;
    const int row16 = lane & 15, kgrp = lane >> 4;      // A: m=row16, k=kgrp*8+e
    const int i0 = blockIdx.x * 64 + wave * 16;
    const int m = i0 + row16;

    f32x4 acc[8] = {};
    const float4* hp = (const float4*)(h + (size_t)m * IN_F);

    float4 c0 = hp[kgrp * 2], c1 = hp[kgrp * 2 + 1];    // prefetch k-iter 0
    for (int kk = 0; kk < IN_F; kk += 32) {
        float4 u0 = c0, u1 = c1;
        if (kk + 32 < IN_F) {                           // prefetch next k-iter
            c0 = hp[(kk + 32) / 4 + kgrp * 2];
            c1 = hp[(kk + 32) / 4 + kgrp * 2 + 1];
        }
        bf16x8 af;
        af[0] = f2bf(u0.x); af[1] = f2bf(u0.y); af[2] = f2bf(u0.z); af[3] = f2bf(u0.w);
        af[4] = f2bf(u1.x); af[5] = f2bf(u1.y); af[6] = f2bf(u1.z); af[7] = f2bf(u1.w);
#pragma unroll
        for (int nt = 0; nt < 8; nt++) {
            bf16x8 bf_ = *(const bf16x8*)(WT + (size_t)(nt * 16 + row16) * IN_F + kk + kgrp * 8);
            acc[nt] = __builtin_amdgcn_mfma_f32_16x16x32_bf16(af, bf_, acc[nt], 0, 0, 0);
        }
    }
    // store WhT: C layout col=row16(n-tile), row=kgrp*4+r (m within 16)
#pragma unroll
    for (int nt = 0; nt < 8; nt++) {
        short4 sv;
        sv.x = f2bf(acc[nt][0]); sv.y = f2bf(acc[nt][1]);
        sv.z = f2bf(acc[nt][2]); sv.w = f2bf(acc[nt][3]);
        *(short4*)(WhT + (size_t)(nt * 16 + row16) * N + i0 + kgrp * 4) = sv;
    }
    // fused s = Wh@a1, t = Wh@a2 (per-lane partial over its 8 cols, reduce over row16 lanes)
    float a1c[8], a2c[8];
#pragma unroll
    for (int nt = 0; nt < 8; nt++) {
        a1c[nt] = a[nt * 16 + row16];
        a2c[nt] = a[OUT_F + nt * 16 + row16];
    }
#pragma unroll
    for (int r = 0; r < 4; r++) {
        float sv = 0.f, tv = 0.f;
#pragma unroll
        for (int nt = 0; nt < 8; nt++) { sv += acc[nt][r] * a1c[nt]; tv += acc[nt][r] * a2c[nt]; }
        sv += __shfl_xor(sv, 1); tv += __shfl_xor(tv, 1);
        sv += __shfl_xor(sv, 2); tv += __shfl_xor(tv, 2);
        sv += __shfl_xor(sv, 4); tv += __shfl_xor(tv, 4);
        sv += __shfl_xor(sv, 8); tv += __shfl_xor(tv, 8);
        if (row16 == 0) {
            sOut[i0 + kgrp * 4 + r] = sv;
            tOut[i0 + kgrp * 4 + r] = tv;
        }
    }
}

// ---------------------------------------------------------------- P2: fused attention, full-j per block
// block = 16 rows, 4 waves split j (2048 each); contiguous 128B/lane adj super-blocks, double-buffered
#define JW 2048          // j per wave
#define SUPER 16         // super-iters of 128 j per wave
__global__ __launch_bounds__(256, 2) void attn(const int* __restrict__ adj,
                                               const short* __restrict__ WhT,
                                               const float* __restrict__ s,
                                               const float* __restrict__ t,
                                               const float* __restrict__ rnd,
                                               float* __restrict__ out) {
    const int tid = threadIdx.x;
    const int wave = tid >> 6, lane = tid & 63;
    const int row16 = lane & 15, kgrp = lane >> 4;
    const int i0 = blockIdx.x * 16;
    const int m = i0 + row16;
    const int jw = wave * JW;

    __shared__ float tl[N];              // 32 KB: all of t
    __shared__ float red[16 * OUT_F];    // 8 KB: cross-wave acc reduce
    __shared__ float lred[64];           // per-wave row sums

    {
        const float4* ts = (const float4*)t;
        float4* td = (float4*)tl;
        for (int i = tid; i < N / 4; i += 256) td[i] = ts[i];
    }
    __syncthreads();

    const float s_m = s[m];
    f32x4 acc[8] = {};
    float lsum = 0.f;

    // lane's adj stream: row m, 32 contiguous ints per super-iter at j = jw + ss*128 + kgrp*32
    const int4* ap = (const int4*)(adj + (size_t)m * N + jw + kgrp * 32);

    int4 bufA[8], bufB[8];
#pragma unroll
    for (int q = 0; q < 8; q++) bufA[q] = ap[q];

    auto process = [&](const int4* buf, int ss) {
        const int j0s = jw + ss * 128;
        const int* bi = (const int*)buf;
#pragma unroll
        for (int p = 0; p < 4; p++) {
            // permuted j for k=kgrp*8+e:  j = j0s + kgrp*32 + p*8 + e  (A and B agree)
            const float* tp = tl + j0s + kgrp * 32 + p * 8;
            float4 tA = *(const float4*)(tp);
            float4 tB = *(const float4*)(tp + 4);
            float tv[8] = { tA.x, tA.y, tA.z, tA.w, tB.x, tB.y, tB.z, tB.w };
            bf16x8 af;
#pragma unroll
            for (int e = 0; e < 8; e++) {
                float x = s_m + tv[e];
                x = fmaxf(x, ALPHA * x);                    // leaky relu
                float pv = bi[p * 8 + e] > 0 ? __expf(x) : 0.f;
                lsum += pv;
                af[e] = f2bf(pv);
            }
#pragma unroll
            for (int nt = 0; nt < 8; nt++) {
                bf16x8 bfr = *(const bf16x8*)(WhT + (size_t)(nt * 16 + row16) * N + j0s + kgrp * 32 + p * 8);
                acc[nt] = __builtin_amdgcn_mfma_f32_16x16x32_bf16(af, bfr, acc[nt], 0, 0, 0);
            }
        }
    };

    for (int ss = 0; ss < SUPER; ss += 2) {
        {   // prefetch ss+1
            const int4* p1 = ap + (ss + 1) * 8;
#pragma unroll
            for (int q = 0; q < 8; q++) bufB[q] = p1[q];
        }
        process(bufA, ss);
        if (ss + 2 < SUPER) {   // prefetch ss+2
            const int4* p2 = ap + (ss + 2) * 8;
#pragma unroll
            for (int q = 0; q < 8; q++) bufA[q] = p2[q];
        }
        process(bufB, ss + 1);
    }

    // per-wave row sums -> lred
    lsum += __shfl_xor(lsum, 16);
    lsum += __shfl_xor(lsum, 32);
    if (kgrp == 0) lred[wave * 16 + row16] = lsum;

    // staged cross-wave acc reduce into red[16][128]
    for (int w = 0; w < 4; w++) {
        if (wave == w) {
#pragma unroll
            for (int nt = 0; nt < 8; nt++)
#pragma unroll
                for (int r = 0; r < 4; r++) {
                    int idx = (kgrp * 4 + r) * OUT_F + nt * 16 + row16;
                    if (w == 0) red[idx] = acc[nt][r];
                    else        red[idx] += acc[nt][r];
                }
        }
        __syncthreads();
    }

    // epilogue: /l, +rnd, *1e-5, elu, store
    const int row = tid >> 4;              // 0..15
    const int c = (tid & 15) * 8;
    float l = lred[row] + lred[16 + row] + lred[32 + row] + lred[48 + row];
    float inv = 1.f / fmaxf(l, 1e-30f);
    size_t g = ((size_t)(i0 + row)) * OUT_F + c;
    float4 r0 = *(const float4*)(rnd + g);
    float4 r1 = *(const float4*)(rnd + g + 4);
    float rv[8] = { r0.x, r0.y, r0.z, r0.w, r1.x, r1.y, r1.z, r1.w };
    float ov[8];
#pragma unroll
    for (int e = 0; e < 8; e++) {
        float hp = red[row * OUT_F + c + e] * inv;
        float x = (hp + rv[e]) * 1e-5f;
        ov[e] = x > 0.f ? x : __expf(x) - 1.f;
    }
    *(float4*)(out + g)     = make_float4(ov[0], ov[1], ov[2], ov[3]);
    *(float4*)(out + g + 4) = make_float4(ov[4], ov[5], ov[6], ov[7]);
}

extern "C" void kernel_launch(void* const* d_in, const int* in_sizes, int n_in,
                              void* d_out, int out_size, void* d_ws, size_t ws_size,
                              hipStream_t stream) {
    const float* h   = (const float*)d_in[0];
    const int*   adj = (const int*)d_in[1];
    const float* W   = (const float*)d_in[2];
    const float* a   = (const float*)d_in[3];
    const float* rnd = (const float*)d_in[4];
    float* out = (float*)d_out;

    char* w = (char*)d_ws;
    short* WT  = (short*)(w);                    // 128*512*2  = 131072
    short* WhT = (short*)(w + 131072);           // 128*8192*2 = 2097152
    float* sv  = (float*)(w + 2228224);          // 32768
    float* tv  = (float*)(w + 2260992);          // 32768  (end ~2.3 MB)

    conv_W <<<256, 256, 0, stream>>>(W, WT);
    gemm_hW<<<128, 256, 0, stream>>>(h, WT, a, WhT, sv, tv);
    attn   <<<N / 16, 256, 0, stream>>>(adj, WhT, sv, tv, rnd, out);
}

// Round 3
// 446.902 us; speedup vs baseline: 1.1684x; 1.1122x over previous
//
#include <hip/hip_runtime.h>

#define N 8192
#define IN_F 512
#define OUT_F 128
#define NW (N / 8)              // 1024 mask bytes per row
#define SPLITK 16
#define LOG2E 1.4426950408889634f
#define LN2 0.6931471805599453f

typedef __attribute__((ext_vector_type(4))) float f32x4;
typedef __attribute__((ext_vector_type(8))) short bf16x8;

__device__ __forceinline__ short f2bf(float f) {
    union { float f; unsigned u; } c; c.f = f;
    unsigned r = c.u + 0x7FFFu + ((c.u >> 16) & 1u);
    return (short)(r >> 16);
}

__device__ __forceinline__ float exp2fast(float x) {
#if __has_builtin(__builtin_amdgcn_exp2f)
    return __builtin_amdgcn_exp2f(x);
#else
    return __expf(x * LN2);
#endif
}

// ---------------------------------------------------------------- conv_W: W -> WT bf16 [OUT_F][IN_F]
__global__ __launch_bounds__(256) void conv_W(const float* __restrict__ W, short* __restrict__ WT) {
    int idx = blockIdx.x * 256 + threadIdx.x;
    int n = idx & (OUT_F - 1);
    int k = idx >> 7;
    WT[(size_t)n * IN_F + k] = f2bf(W[idx]);
}

// ---------------------------------------------------------------- mkmask: adj int32 -> row-major bitmask
// wave handles one row; fully coalesced 2KB reads, 64B byte-stores
__global__ __launch_bounds__(256) void mkmask(const int* __restrict__ adj,
                                              unsigned char* __restrict__ maskR) {
    const int wave = threadIdx.x >> 6, lane = threadIdx.x & 63;
    const size_t m = (size_t)blockIdx.x * 4 + wave;
    const int4* ap = (const int4*)(adj + m * N);
    unsigned char* mp = maskR + m * NW;
#pragma unroll 4
    for (int it = 0; it < 16; it++) {
        int b4 = it * 128 + lane * 2;
        int4 a0 = ap[b4], a1 = ap[b4 + 1];
        unsigned b = (unsigned)(a0.x > 0) | ((unsigned)(a0.y > 0) << 1) |
                     ((unsigned)(a0.z > 0) << 2) | ((unsigned)(a0.w > 0) << 3) |
                     ((unsigned)(a1.x > 0) << 4) | ((unsigned)(a1.y > 0) << 5) |
                     ((unsigned)(a1.z > 0) << 6) | ((unsigned)(a1.w > 0) << 7);
        mp[it * 64 + lane] = (unsigned char)b;
    }
}

// ---------------------------------------------------------------- gemm_hW: Wh=h@W -> WhT bf16 [OUT_F][N]; fused s,t (x LOG2E)
// 512 blocks: 16 rows/block, 4 waves split K, LDS reduce
__global__ __launch_bounds__(256) void gemm_hW(const float* __restrict__ h,
                                               const short* __restrict__ WT,
                                               const float* __restrict__ a,
                                               short* __restrict__ WhT,
                                               float* __restrict__ sOut,
                                               float* __restrict__ tOut) {
    const int tid = threadIdx.x;
    const int wave = tid >> 6, lane = tid & 63;
    const int row16 = lane & 15, kgrp = lane >> 4;
    const int m0 = blockIdx.x * 16;
    const int kbase = wave * 128;

    f32x4 acc[8] = {};
    const float4* hp = (const float4*)(h + (size_t)(m0 + row16) * IN_F + kbase);

#pragma unroll
    for (int kk = 0; kk < 128; kk += 32) {
        float4 u0 = hp[kk / 4 + kgrp * 2];
        float4 u1 = hp[kk / 4 + kgrp * 2 + 1];
        bf16x8 af;
        af[0] = f2bf(u0.x); af[1] = f2bf(u0.y); af[2] = f2bf(u0.z); af[3] = f2bf(u0.w);
        af[4] = f2bf(u1.x); af[5] = f2bf(u1.y); af[6] = f2bf(u1.z); af[7] = f2bf(u1.w);
#pragma unroll
        for (int nt = 0; nt < 8; nt++) {
            bf16x8 bf_ = *(const bf16x8*)(WT + (size_t)(nt * 16 + row16) * IN_F + kbase + kk + kgrp * 8);
            acc[nt] = __builtin_amdgcn_mfma_f32_16x16x32_bf16(af, bf_, acc[nt], 0, 0, 0);
        }
    }

    __shared__ float red[4][16][132];     // +4 pad: kgrp stride 528 -> 2-way max (free)
#pragma unroll
    for (int nt = 0; nt < 8; nt++)
#pragma unroll
        for (int r = 0; r < 4; r++)
            red[wave][kgrp * 4 + r][nt * 16 + row16] = acc[nt][r];
    __syncthreads();

    const int row = tid >> 4, seg = tid & 15;
    float v[8];
#pragma unroll
    for (int e = 0; e < 8; e++) {
        int c = seg * 8 + e;
        v[e] = red[0][row][c] + red[1][row][c] + red[2][row][c] + red[3][row][c];
    }
    float sp = 0.f, tp = 0.f;
#pragma unroll
    for (int e = 0; e < 8; e++) {
        sp += v[e] * a[seg * 8 + e];
        tp += v[e] * a[OUT_F + seg * 8 + e];
    }
    sp += __shfl_xor(sp, 1); tp += __shfl_xor(tp, 1);
    sp += __shfl_xor(sp, 2); tp += __shfl_xor(tp, 2);
    sp += __shfl_xor(sp, 4); tp += __shfl_xor(tp, 4);
    sp += __shfl_xor(sp, 8); tp += __shfl_xor(tp, 8);
    if (seg == 0) {
        sOut[m0 + row] = sp * LOG2E;      // pre-scale so attn uses 2^x
        tOut[m0 + row] = tp * LOG2E;
    }
#pragma unroll
    for (int e = 0; e < 8; e++)
        WhT[(size_t)(seg * 8 + e) * N + m0 + row] = f2bf(v[e]);
}

// ---------------------------------------------------------------- attn: C_partial = P(mask,s,t) @ Wh, split-K
// grid (16 mblocks, 16 ksplits), 512 thr = 8 waves, wave = 64M x 128N, K-chunk 512
__global__ __launch_bounds__(512, 2) void attn(const unsigned char* __restrict__ maskR,
                                               const short* __restrict__ WhT,
                                               const float* __restrict__ s,
                                               const float* __restrict__ t,
                                               float* __restrict__ num,
                                               float* __restrict__ lpart) {
    const int tid = threadIdx.x;
    const int wave = tid >> 6, lane = tid & 63;
    const int row16 = lane & 15, kgrp = lane >> 4;
    const int m0 = blockIdx.x * 512 + wave * 64;
    const int ks = blockIdx.y * 512;

    __shared__ float tl[512];
    if (tid < 512) tl[tid] = t[ks + tid];
    __syncthreads();

    float s_m[4];
    const unsigned long long* mrow[4];
#pragma unroll
    for (int mi = 0; mi < 4; mi++) {
        int m = m0 + mi * 16 + row16;
        s_m[mi] = s[m];
        mrow[mi] = (const unsigned long long*)(maskR + (size_t)m * NW + (ks >> 3));
    }

    f32x4 acc[4][8] = {};
    float lsum[4] = {0.f, 0.f, 0.f, 0.f};

    unsigned long long mcur[4], mnxt[4];
#pragma unroll
    for (int mi = 0; mi < 4; mi++) { mcur[mi] = mrow[mi][0]; mnxt[mi] = mrow[mi][1]; }

    for (int c2 = 0; c2 < 8; c2++) {        // 64-k super-chunks
        unsigned long long mk[4];
#pragma unroll
        for (int mi = 0; mi < 4; mi++) { mk[mi] = mcur[mi]; mcur[mi] = mnxt[mi]; }
        if (c2 < 6) {
#pragma unroll
            for (int mi = 0; mi < 4; mi++) mnxt[mi] = mrow[mi][c2 + 2];
        }
#pragma unroll
        for (int cc = 0; cc < 2; cc++) {    // 32-k MFMA chunks
            const int k0 = c2 * 64 + cc * 32;
            const float* tp = tl + k0 + kgrp * 8;
            float4 tA = *(const float4*)tp;
            float4 tB = *(const float4*)(tp + 4);
            float tv[8] = { tA.x, tA.y, tA.z, tA.w, tB.x, tB.y, tB.z, tB.w };

            bf16x8 bfr[8];
            const short* bb = WhT + ks + k0 + kgrp * 8;
#pragma unroll
            for (int ni = 0; ni < 8; ni++)
                bfr[ni] = *(const bf16x8*)(bb + (size_t)(ni * 16 + row16) * N);

#pragma unroll
            for (int mi = 0; mi < 4; mi++) {
                unsigned bbyte = (unsigned)(mk[mi] >> (cc * 32 + kgrp * 8)) & 0xFFu;
                unsigned pu[8];
#pragma unroll
                for (int e = 0; e < 8; e++) {
                    float x = s_m[mi] + tv[e];
                    x = fmaxf(x, 0.2f * x);                 // leaky relu (scale-invariant)
                    float p = exp2fast(x);                  // s,t pre-scaled by log2e
                    unsigned u = __float_as_uint(p) & 0xFFFF0000u;   // trunc to bf16
                    u = ((bbyte >> e) & 1u) ? u : 0u;
                    lsum[mi] += __uint_as_float(u);         // consistent with numerator
                    pu[e] = u;
                }
                bf16x8 af;
                unsigned* au = (unsigned*)&af;
#pragma unroll
                for (int q = 0; q < 4; q++) au[q] = (pu[2 * q] >> 16) | pu[2 * q + 1];
#pragma unroll
                for (int ni = 0; ni < 8; ni++)
                    acc[mi][ni] = __builtin_amdgcn_mfma_f32_16x16x32_bf16(af, bfr[ni], acc[mi][ni], 0, 0, 0);
            }
        }
    }

#pragma unroll
    for (int mi = 0; mi < 4; mi++) {
        float v = lsum[mi];
        v += __shfl_xor(v, 16);
        v += __shfl_xor(v, 32);
        if (kgrp == 0) lpart[(size_t)blockIdx.y * N + m0 + mi * 16 + row16] = v;
    }

    float* np_ = num + (size_t)blockIdx.y * N * OUT_F;
#pragma unroll
    for (int mi = 0; mi < 4; mi++) {
        int mb = m0 + mi * 16 + kgrp * 4;   // C layout: row = kgrp*4+r, col = row16
#pragma unroll
        for (int ni = 0; ni < 8; ni++) {
            int n = ni * 16 + row16;
#pragma unroll
            for (int r = 0; r < 4; r++)
                np_[(size_t)(mb + r) * OUT_F + n] = acc[mi][ni][r];
        }
    }
}

// ---------------------------------------------------------------- finalize: reduce splits, /l, +rnd, elu
__global__ __launch_bounds__(256) void finalize(const float* __restrict__ num,
                                                const float* __restrict__ lpart,
                                                const float* __restrict__ rnd,
                                                float* __restrict__ out) {
    int idx = blockIdx.x * 256 + threadIdx.x;
    int m = idx >> 7;
    float l = 0.f, nm = 0.f;
#pragma unroll
    for (int bk = 0; bk < SPLITK; bk++) {
        l  += lpart[bk * N + m];
        nm += num[(size_t)bk * N * OUT_F + idx];
    }
    float hp = nm / fmaxf(l, 1e-30f);
    float x = (hp + rnd[idx]) * 1e-5f;
    out[idx] = x > 0.f ? x : __expf(x) - 1.f;
}

extern "C" void kernel_launch(void* const* d_in, const int* in_sizes, int n_in,
                              void* d_out, int out_size, void* d_ws, size_t ws_size,
                              hipStream_t stream) {
    const float* h   = (const float*)d_in[0];
    const int*   adj = (const int*)d_in[1];
    const float* W   = (const float*)d_in[2];
    const float* a   = (const float*)d_in[3];
    const float* rnd = (const float*)d_in[4];
    float* out = (float*)d_out;

    char* w = (char*)d_ws;
    short* WT    = (short*)(w);                         // 131072
    short* WhT   = (short*)(w + 131072);                // 2097152 -> 2228224
    float* sv    = (float*)(w + 2228224);               // 32768   -> 2260992
    float* tv    = (float*)(w + 2260992);               // 32768   -> 2293760
    float* lpart = (float*)(w + 2293760);               // 524288  -> 2818048
    unsigned char* maskR = (unsigned char*)(w + 2818048); // 8388608 -> 11206656
    float* num   = (float*)(w + 11206656);              // 67108864 -> 78315520 (~75 MB)

    conv_W  <<<256, 256, 0, stream>>>(W, WT);
    mkmask  <<<2048, 256, 0, stream>>>(adj, maskR);
    gemm_hW <<<512, 256, 0, stream>>>(h, WT, a, WhT, sv, tv);
    attn    <<<dim3(16, SPLITK), 512, 0, stream>>>(maskR, WhT, sv, tv, num, lpart);
    finalize<<<(N * OUT_F) / 256, 256, 0, stream>>>(num, lpart, rnd, out);
}